// Round 8
// baseline (104.563 us; speedup 1.0000x reference)
//
#include <hip/hip_runtime.h>
#include <hip/hip_bf16.h>

#define N 8192
#define D 256
#define NSLICE 32
#define BM 256                       // rows per block (4 waves x 64 rows)
#define TROWS 4                      // row-tiles of 16 per wave
#define CB 16                        // cols per staged LDS tile
#define COLS_PER_SLICE (N / NSLICE)  // 256
#define NT (COLS_PER_SLICE / CB)     // 16 tiles per block
#define NRB (N / BM)                 // 32 row blocks
#define TILE_E (CB * D)              // 4096 ushorts = 8 KB per tile

#define CSHIFT 160.0f                // fixed base-2 LSE shift
#define K2LOG2E 2.885390082f         // (1/T) * log2(e) = 2 * 1.44269504
#define LN2F 0.6931471805599453f

typedef __attribute__((ext_vector_type(8))) short bf16x8;
typedef __attribute__((ext_vector_type(4))) float f32x4;

__device__ inline float fast_exp2(float x) { return __builtin_amdgcn_exp2f(x); }
__device__ inline float fast_log2(float x) { return __builtin_amdgcn_logf(x); }

// async global->LDS, 16B per lane; LDS dest = wave-uniform base + lane*16,
// global src is per-lane (carries the fragment layout).
__device__ inline void gload_lds16(const ushort* g, ushort* l) {
    __builtin_amdgcn_global_load_lds(
        (const __attribute__((address_space(1))) void*)g,
        (__attribute__((address_space(3))) void*)l, 16, 0, 0);
}

__device__ inline ushort f2bf(float x) {
    __hip_bfloat16 h = __float2bfloat16(x);
    return *reinterpret_cast<ushort*>(&h);
}

// ---------------- kernel 0: fp32 -> bf16 conversion + fused label histogram ----------------
__global__ void convert_bf16(const float* __restrict__ F, const float* __restrict__ Imp,
                             ushort* __restrict__ Fb, ushort* __restrict__ Ib,
                             const int* __restrict__ labels, int* __restrict__ counts) {
    const int i = blockIdx.x * blockDim.x + threadIdx.x;  // float4 index
    const int total4 = N * D / 4;
    const float4* src = (blockIdx.y == 0) ? (const float4*)F : (const float4*)Imp;
    ushort* dst = (blockIdx.y == 0) ? Fb : Ib;
    if (i < total4) {
        float4 v = src[i];
        ushort4 o;
        o.x = f2bf(v.x); o.y = f2bf(v.y); o.z = f2bf(v.z); o.w = f2bf(v.w);
        *reinterpret_cast<ushort4*>(dst + 4 * (size_t)i) = o;
    }
    // fused histogram: first 32 x-blocks of y==0 cover the 8192 labels
    if (blockIdx.y == 0 && blockIdx.x < 32) {
        const int li = blockIdx.x * 256 + threadIdx.x;
        atomicAdd(&counts[labels[li]], 1);  // counts pre-zeroed via hipMemsetAsync
    }
}

// ---------------- kernel 1: single-pass tile kernel ----------------
// 64 rows/wave (4 row-tiles in registers): each 8x ds_read_b128 B-fragment
// feeds 32 MFMAs. 29KB LDS + grid 1024 -> 4 blocks/CU (4 waves/SIMD).
// Triple-buffered staging, counted vmcnt, raw s_barrier, setprio.
// NOTE: launch_bounds kept at (256,2): a tighter cap (128 VGPR) spills afrag
// to scratch -> r5's FETCH/WRITE explosion. Occupancy comes from actual use.
// blockIdx.x: row block (256 rows), blockIdx.y: column slice (256 cols).
__launch_bounds__(256, 2)
__global__ void tile_pass(const ushort* __restrict__ Fb, const ushort* __restrict__ Ib,
                          const int* __restrict__ labels,
                          float* __restrict__ partials_row,    // [N][NSLICE]
                          float* __restrict__ partials_col) {  // [NRB][N]
    __shared__ ushort Bsh[3 * TILE_E];              // 3 x 8KB, fragment-ordered
    __shared__ float colacc[4][COLS_PER_SLICE];     // 4KB, per-wave private rows
    __shared__ int labs[COLS_PER_SLICE];            // 1KB

    const int tid = threadIdx.x;
    const int lane = tid & 63;
    const int wave = tid >> 6;
    const int rb = blockIdx.x;
    const int row0 = rb * BM + wave * (16 * TROWS); // 4 row-tiles of 16
    const int c0 = blockIdx.y * COLS_PER_SLICE;
    const int lrow = lane & 15;                     // A-row / B-col within tile
    const int kgrp = lane >> 4;                     // 0..3

    // stage a 16-col tile: 8 chunks of 1KB; wave w stages chunks 2w, 2w+1.
    // chunk layout: lane l's 16B at chunk*1KB + l*16 = B[cbase+(l&15)][ks*32+(l>>4)*8 ..+7], ks=chunk
#define STAGE(buf, ct)                                                                  \
    {                                                                                   \
        const int cbase = c0 + (ct) * CB;                                               \
        _Pragma("unroll")                                                               \
        for (int i = 0; i < 2; ++i) {                                                   \
            const int ks = wave * 2 + i;                                                \
            const ushort* src =                                                         \
                Ib + (size_t)(cbase + lrow) * D + ks * 32 + kgrp * 8;                   \
            gload_lds16(src, &Bsh[(buf) * TILE_E + ks * 512]);                          \
        }                                                                               \
    }

    STAGE(0, 0);
    STAGE(1, 1);

    // init colacc + label cache while loads fly
    for (int i = tid; i < COLS_PER_SLICE; i += 256) {
        labs[i] = labels[c0 + i];
        colacc[0][i] = 0.f; colacc[1][i] = 0.f; colacc[2][i] = 0.f; colacc[3][i] = 0.f;
    }

    // A fragments held in registers for the whole block (4 tiles x K=256)
    bf16x8 afrag[TROWS][8];
#pragma unroll
    for (int t = 0; t < TROWS; ++t) {
        const ushort* arow = Fb + (size_t)(row0 + t * 16 + lrow) * D;
#pragma unroll
        for (int ks = 0; ks < 8; ++ks)
            afrag[t][ks] = *reinterpret_cast<const bf16x8*>(arow + ks * 32 + kgrp * 8);
    }

    int labr[TROWS][4];
#pragma unroll
    for (int t = 0; t < TROWS; ++t)
#pragma unroll
        for (int r = 0; r < 4; ++r)
            labr[t][r] = labels[row0 + t * 16 + kgrp * 4 + r];

    float s[TROWS][4];
#pragma unroll
    for (int t = 0; t < TROWS; ++t)
#pragma unroll
        for (int r = 0; r < 4; ++r) s[t][r] = 0.0f;

    // tile 0 landed (tile 1 may still fly); LDS writes (labs/colacc) visible
    asm volatile("s_waitcnt vmcnt(2) lgkmcnt(0)" ::: "memory");
    __builtin_amdgcn_s_barrier();

    int cbuf = 0, sbuf = 2;
    for (int ct = 0; ct < NT; ++ct) {
        if (ct + 2 < NT) STAGE(sbuf, ct + 2);  // keep 2 tiles in flight

        __builtin_amdgcn_s_setprio(1);
        bf16x8 bfrag[8];
#pragma unroll
        for (int ks = 0; ks < 8; ++ks)
            bfrag[ks] = *reinterpret_cast<const bf16x8*>(
                &Bsh[cbuf * TILE_E + ks * 512 + lane * 8]);  // linear: conflict-free

        const int labc = labs[ct * CB + lrow];
        float colpart = 0.0f;
        f32x4 acc[TROWS];
#pragma unroll
        for (int t = 0; t < TROWS; ++t) acc[t] = f32x4{0.f, 0.f, 0.f, 0.f};
        // ks outer / t inner: 4 independent MFMA chains interleaved (ILP)
#pragma unroll
        for (int ks = 0; ks < 8; ++ks)
#pragma unroll
            for (int t = 0; t < TROWS; ++t)
                acc[t] = __builtin_amdgcn_mfma_f32_16x16x32_bf16(afrag[t][ks], bfrag[ks], acc[t], 0, 0, 0);

#pragma unroll
        for (int t = 0; t < TROWS; ++t) {
            // D layout: col = lane&15, row = (lane>>4)*4 + r
#pragma unroll
            for (int r = 0; r < 4; ++r) {
                float arg = __builtin_fmaf(acc[t][r], K2LOG2E, -CSHIFT);
                arg = (labr[t][r] == labc) ? -1000.0f : arg;  // masked (incl. diag) -> 0
                float e = fast_exp2(arg);
                s[t][r] += e;
                colpart += e;
            }
        }
        // col-sum over this wave's 64 rows: reduce across kgrp lane groups
        colpart += __shfl_xor(colpart, 16, 64);
        colpart += __shfl_xor(colpart, 32, 64);
        if (kgrp == 0)
            colacc[wave][ct * CB + lrow] += colpart;
        __builtin_amdgcn_s_setprio(0);

        // counted wait: next tile landed, tile-after stays in flight (T4)
        if (ct + 2 < NT) {
            asm volatile("s_waitcnt vmcnt(2)" ::: "memory");
        } else {
            asm volatile("s_waitcnt vmcnt(0)" ::: "memory");
        }
        __builtin_amdgcn_s_barrier();
        cbuf = (cbuf == 2) ? 0 : cbuf + 1;
        sbuf = (sbuf == 2) ? 0 : sbuf + 1;
    }

    // row partials: sum the 16 lrow-lanes (disjoint column subsets)
#pragma unroll
    for (int off = 1; off < 16; off <<= 1) {
#pragma unroll
        for (int t = 0; t < TROWS; ++t)
#pragma unroll
            for (int r = 0; r < 4; ++r)
                s[t][r] += __shfl_xor(s[t][r], off, 64);
    }
    if (lrow == 0) {
#pragma unroll
        for (int t = 0; t < TROWS; ++t)
#pragma unroll
            for (int r = 0; r < 4; ++r) {
                const int grow = row0 + t * 16 + kgrp * 4 + r;
                partials_row[(size_t)grow * NSLICE + blockIdx.y] = s[t][r];
            }
    }

    __syncthreads();  // all colacc writes visible
    for (int i = tid; i < COLS_PER_SLICE; i += 256) {
        float v = colacc[0][i] + colacc[1][i] + colacc[2][i] + colacc[3][i];
        partials_col[(size_t)rb * N + c0 + i] = v;
    }
#undef STAGE
}

// exact lse over { S*2^CSHIFT (bulk), cnt*exp(0), exp(diag) }
__device__ inline float final_lse(float S, float cntlog, float diag) {
    float l1 = (S > 0.0f) ? (CSHIFT + fast_log2(S)) * LN2F : -INFINITY;
    float M = fmaxf(fmaxf(l1, cntlog), diag);  // M finite: diag always finite
    return M + __logf(__expf(l1 - M) + __expf(cntlog - M) + __expf(diag - M));
}

// ---------------- kernel 2: per-row contribution (wave per row, fused col reduce) ----------------
__global__ void row_contrib(const float* __restrict__ F, const float* __restrict__ Imp,
                            const float* __restrict__ partials_row,
                            const float* __restrict__ partials_col,
                            const int* __restrict__ counts,
                            const int* __restrict__ labels, float* __restrict__ blockSums) {
    const int lane = threadIdx.x & 63;
    const int wave = threadIdx.x >> 6;
    const int row = blockIdx.x * 4 + wave;

    // fp32 diagonal dot: 256 floats = 64 lanes * float4
    float4 a = reinterpret_cast<const float4*>(F + (size_t)row * D)[lane];
    float4 b = reinterpret_cast<const float4*>(Imp + (size_t)row * D)[lane];
    float dot = a.x * b.x + a.y * b.y + a.z * b.z + a.w * b.w;
#pragma unroll
    for (int off = 32; off > 0; off >>= 1) dot += __shfl_xor(dot, off, 64);

    // S_row: 32 slice partials; S_col: 32 row-block partials (lanes 0..31)
    float sr = (lane < NSLICE) ? partials_row[(size_t)row * NSLICE + lane] : 0.0f;
    float sc = (lane < NRB) ? partials_col[(size_t)lane * N + row] : 0.0f;
#pragma unroll
    for (int off = 16; off > 0; off >>= 1) {
        sr += __shfl_xor(sr, off, 64);
        sc += __shfl_xor(sc, off, 64);
    }

    __shared__ float sums[4];
    if (lane == 0) {
        const float diag = 2.0f * dot;                 // temperature 0.5
        const int cnt = counts[labels[row]] - 1;       // equal-label count excl. self
        const float cntlog = (cnt > 0) ? __logf((float)cnt) : -INFINITY;
        const float lse_total = final_lse(sr, cntlog, diag) + final_lse(sc, cntlog, diag);
        sums[wave] = 2.0f * diag - lse_total;
    }
    __syncthreads();
    if (threadIdx.x == 0)
        blockSums[blockIdx.x] = sums[0] + sums[1] + sums[2] + sums[3];
}

// ---------------- kernel 3: final deterministic reduce ----------------
__global__ void final_reduce(const float* __restrict__ blockSums, float* __restrict__ out) {
    __shared__ float red[256];
    float v = 0.0f;
    for (int i = threadIdx.x; i < N / 4; i += 256) v += blockSums[i];
    red[threadIdx.x] = v;
    __syncthreads();
    for (int st = 128; st > 0; st >>= 1) {
        if (threadIdx.x < st) red[threadIdx.x] += red[threadIdx.x + st];
        __syncthreads();
    }
    if (threadIdx.x == 0) out[0] = -red[0] / (float)N;
}

extern "C" void kernel_launch(void* const* d_in, const int* in_sizes, int n_in,
                              void* d_out, int out_size, void* d_ws, size_t ws_size,
                              hipStream_t stream) {
    const float* F = (const float*)d_in[0];
    const float* Imp = (const float*)d_in[1];
    const int* labels = (const int*)d_in[2];
    float* out = (float*)d_out;

    char* ws = (char*)d_ws;
    size_t off = 0;
    ushort* Fb = (ushort*)(ws + off); off += (size_t)N * D * 2;               // 4 MB
    ushort* Ib = (ushort*)(ws + off); off += (size_t)N * D * 2;               // 4 MB
    float* partials_row = (float*)(ws + off); off += (size_t)N * NSLICE * 4;  // 1 MB
    float* partials_col = (float*)(ws + off); off += (size_t)NRB * N * 4;     // 1 MB
    float* blockSums = (float*)(ws + off); off += (size_t)(N / 4) * 4;        // 8 KB
    int* counts = (int*)(ws + off);

    hipMemsetAsync(counts, 0, 16 * sizeof(int), stream);

    dim3 cgrid((N * D / 4 + 255) / 256, 2);
    convert_bf16<<<cgrid, 256, 0, stream>>>(F, Imp, Fb, Ib, labels, counts);

    dim3 g(NRB, NSLICE);
    tile_pass<<<g, 256, 0, stream>>>(Fb, Ib, labels, partials_row, partials_col);

    row_contrib<<<N / 4, 256, 0, stream>>>(F, Imp, partials_row, partials_col, counts, labels, blockSums);
    final_reduce<<<1, 256, 0, stream>>>(blockSums, out);
}

// Round 9
// 81.111 us; speedup vs baseline: 1.2891x; 1.2891x over previous
//
#include <hip/hip_runtime.h>
#include <hip/hip_bf16.h>

#define N 8192
#define D 256
#define NSLICE 32
#define BM 256                       // rows per block (4 waves x 64 rows)
#define TROWS 4                      // row-tiles of 16 per wave
#define CB 32                        // cols per staged LDS tile
#define COLS_PER_SLICE (N / NSLICE)  // 256
#define NT (COLS_PER_SLICE / CB)     // 8 tiles per block
#define NRB (N / BM)                 // 32 row blocks
#define TILE_E (CB * D)              // 8192 ushorts = 16 KB per tile

#define CSHIFT 160.0f                // fixed base-2 LSE shift
#define K2LOG2E 2.885390082f         // (1/T) * log2(e) = 2 * 1.44269504
#define LN2F 0.6931471805599453f

typedef __attribute__((ext_vector_type(8))) short bf16x8;
typedef __attribute__((ext_vector_type(4))) float f32x4;

__device__ inline float fast_exp2(float x) { return __builtin_amdgcn_exp2f(x); }
__device__ inline float fast_log2(float x) { return __builtin_amdgcn_logf(x); }

// async global->LDS, 16B per lane; LDS dest = wave-uniform base + lane*16,
// global src is per-lane (carries the fragment layout).
__device__ inline void gload_lds16(const ushort* g, ushort* l) {
    __builtin_amdgcn_global_load_lds(
        (const __attribute__((address_space(1))) void*)g,
        (__attribute__((address_space(3))) void*)l, 16, 0, 0);
}

__device__ inline ushort f2bf(float x) {
    __hip_bfloat16 h = __float2bfloat16(x);
    return *reinterpret_cast<ushort*>(&h);
}

// ---------------- kernel 0: fp32 -> bf16 conversion ----------------
__global__ void convert_bf16(const float* __restrict__ F, const float* __restrict__ Imp,
                             ushort* __restrict__ Fb, ushort* __restrict__ Ib) {
    const int i = blockIdx.x * blockDim.x + threadIdx.x;  // float4 index
    const int total4 = N * D / 4;
    const float4* src = (blockIdx.y == 0) ? (const float4*)F : (const float4*)Imp;
    ushort* dst = (blockIdx.y == 0) ? Fb : Ib;
    if (i < total4) {
        float4 v = src[i];
        ushort4 o;
        o.x = f2bf(v.x); o.y = f2bf(v.y); o.z = f2bf(v.z); o.w = f2bf(v.w);
        *reinterpret_cast<ushort4*>(dst + 4 * (size_t)i) = o;
    }
}

// ---------------- kernel 0b: label histogram (14 bins) ----------------
__global__ void label_hist(const int* __restrict__ labels, int* __restrict__ counts) {
    __shared__ int c[16];
    if (threadIdx.x < 16) c[threadIdx.x] = 0;
    __syncthreads();
    for (int i = threadIdx.x; i < N; i += blockDim.x) atomicAdd(&c[labels[i]], 1);
    __syncthreads();
    if (threadIdx.x < 16) counts[threadIdx.x] = c[threadIdx.x];
}

// ---------------- kernel 1: single-pass tile kernel ----------------
// 64 rows/wave (4 row-tiles in registers): each 8x ds_read_b128 B-fragment
// feeds 32 MFMAs. Double-buffered LDS (37KB total) + grid 1024 -> target
// 4 blocks/CU; ONE barrier per tile (wave's own ds_reads are consumed
// before it reaches the barrier, so a single vmcnt(0)+s_barrier covers
// both the read-done and stage-landed hazards). No setprio (lockstep).
// blockIdx.x: row block (256 rows), blockIdx.y: column slice (256 cols).
__launch_bounds__(256, 2)
__global__ void tile_pass(const ushort* __restrict__ Fb, const ushort* __restrict__ Ib,
                          const int* __restrict__ labels,
                          float* __restrict__ partials_row,    // [N][NSLICE]
                          float* __restrict__ partials_col) {  // [NRB][N]
    __shared__ ushort Bsh[2 * TILE_E];              // 2 x 16KB, fragment-ordered
    __shared__ float colacc[4][COLS_PER_SLICE];     // 4KB, per-wave private rows
    __shared__ int labs[COLS_PER_SLICE];            // 1KB

    const int tid = threadIdx.x;
    const int lane = tid & 63;
    const int wave = tid >> 6;
    const int rb = blockIdx.x;
    const int row0 = rb * BM + wave * (16 * TROWS); // 4 row-tiles of 16
    const int c0 = blockIdx.y * COLS_PER_SLICE;
    const int lrow = lane & 15;                     // A-row / B-col within tile
    const int kgrp = lane >> 4;                     // 0..3

    // stage a 32-col tile: 16 chunks of 1KB; chunk = u*8+ks; wave w stages 4w..4w+3.
    // chunk layout: lane l's 16B at chunk_base + l*16 = B[cbase+u*16+(l&15)][ks*32+(l>>4)*8 ..+7]
#define STAGE(buf, ct)                                                                  \
    {                                                                                   \
        const int cbase = c0 + (ct) * CB;                                               \
        _Pragma("unroll")                                                               \
        for (int i = 0; i < 4; ++i) {                                                   \
            const int chunk = wave * 4 + i;                                             \
            const int u = chunk >> 3, ks = chunk & 7;                                   \
            const ushort* src =                                                         \
                Ib + (size_t)(cbase + u * 16 + lrow) * D + ks * 32 + kgrp * 8;          \
            gload_lds16(src, &Bsh[(buf) * TILE_E + chunk * 512]);                       \
        }                                                                               \
    }

    STAGE(0, 0);

    // init colacc + label cache while loads fly
    for (int i = tid; i < COLS_PER_SLICE; i += 256) {
        labs[i] = labels[c0 + i];
        colacc[0][i] = 0.f; colacc[1][i] = 0.f; colacc[2][i] = 0.f; colacc[3][i] = 0.f;
    }

    // A fragments held in registers for the whole block (4 tiles x K=256)
    bf16x8 afrag[TROWS][8];
#pragma unroll
    for (int t = 0; t < TROWS; ++t) {
        const ushort* arow = Fb + (size_t)(row0 + t * 16 + lrow) * D;
#pragma unroll
        for (int ks = 0; ks < 8; ++ks)
            afrag[t][ks] = *reinterpret_cast<const bf16x8*>(arow + ks * 32 + kgrp * 8);
    }

    int labr[TROWS][4];
#pragma unroll
    for (int t = 0; t < TROWS; ++t)
#pragma unroll
        for (int r = 0; r < 4; ++r)
            labr[t][r] = labels[row0 + t * 16 + kgrp * 4 + r];

    float s[TROWS][4];
#pragma unroll
    for (int t = 0; t < TROWS; ++t)
#pragma unroll
        for (int r = 0; r < 4; ++r) s[t][r] = 0.0f;

    // tile 0 landed; LDS writes (labs/colacc) visible
    asm volatile("s_waitcnt vmcnt(0) lgkmcnt(0)" ::: "memory");
    __builtin_amdgcn_s_barrier();

    int cur = 0;
    for (int ct = 0; ct < NT; ++ct) {
        if (ct + 1 < NT) STAGE(cur ^ 1, ct + 1);  // prefetch next tile

#pragma unroll
        for (int u = 0; u < 2; ++u) {
            bf16x8 bfrag[8];
#pragma unroll
            for (int ks = 0; ks < 8; ++ks)
                bfrag[ks] = *reinterpret_cast<const bf16x8*>(
                    &Bsh[cur * TILE_E + (u * 8 + ks) * 512 + lane * 8]);  // linear: conflict-free

            const int labc = labs[ct * CB + u * 16 + lrow];
            float colpart = 0.0f;
            f32x4 acc[TROWS];
#pragma unroll
            for (int t = 0; t < TROWS; ++t) acc[t] = f32x4{0.f, 0.f, 0.f, 0.f};
            // ks outer / t inner: 4 independent MFMA chains interleaved (ILP)
#pragma unroll
            for (int ks = 0; ks < 8; ++ks)
#pragma unroll
                for (int t = 0; t < TROWS; ++t)
                    acc[t] = __builtin_amdgcn_mfma_f32_16x16x32_bf16(afrag[t][ks], bfrag[ks], acc[t], 0, 0, 0);

#pragma unroll
            for (int t = 0; t < TROWS; ++t) {
                // D layout: col = lane&15, row = (lane>>4)*4 + r
#pragma unroll
                for (int r = 0; r < 4; ++r) {
                    float arg = __builtin_fmaf(acc[t][r], K2LOG2E, -CSHIFT);
                    arg = (labr[t][r] == labc) ? -1000.0f : arg;  // masked (incl. diag) -> 0
                    float e = fast_exp2(arg);
                    s[t][r] += e;
                    colpart += e;
                }
            }
            // col-sum over this wave's 64 rows: reduce across kgrp lane groups
            colpart += __shfl_xor(colpart, 16, 64);
            colpart += __shfl_xor(colpart, 32, 64);
            if (kgrp == 0)
                colacc[wave][ct * CB + u * 16 + lrow] += colpart;
        }

        // single barrier per tile: my stage landed (vmcnt), my reads consumed
        asm volatile("s_waitcnt vmcnt(0)" ::: "memory");
        __builtin_amdgcn_s_barrier();
        cur ^= 1;
    }

    // row partials: sum the 16 lrow-lanes (disjoint column subsets)
#pragma unroll
    for (int off = 1; off < 16; off <<= 1) {
#pragma unroll
        for (int t = 0; t < TROWS; ++t)
#pragma unroll
            for (int r = 0; r < 4; ++r)
                s[t][r] += __shfl_xor(s[t][r], off, 64);
    }
    if (lrow == 0) {
#pragma unroll
        for (int t = 0; t < TROWS; ++t)
#pragma unroll
            for (int r = 0; r < 4; ++r) {
                const int grow = row0 + t * 16 + kgrp * 4 + r;
                partials_row[(size_t)grow * NSLICE + blockIdx.y] = s[t][r];
            }
    }

    __syncthreads();  // all colacc writes visible
    for (int i = tid; i < COLS_PER_SLICE; i += 256) {
        float v = colacc[0][i] + colacc[1][i] + colacc[2][i] + colacc[3][i];
        partials_col[(size_t)rb * N + c0 + i] = v;
    }
#undef STAGE
}

// ---------------- kernel 1b: reduce col partials over row blocks ----------------
__global__ void col_reduce(const float* __restrict__ partials_col, float* __restrict__ colsum) {
    const int c = blockIdx.x * 256 + threadIdx.x;
    float v = 0.0f;
    for (int rbi = 0; rbi < NRB; ++rbi) v += partials_col[(size_t)rbi * N + c];
    colsum[c] = v;
}

// exact lse over { S*2^CSHIFT (bulk), cnt*exp(0), exp(diag) }
__device__ inline float final_lse(float S, float cntlog, float diag) {
    float l1 = (S > 0.0f) ? (CSHIFT + fast_log2(S)) * LN2F : -INFINITY;
    float M = fmaxf(fmaxf(l1, cntlog), diag);  // M finite: diag always finite
    return M + __logf(__expf(l1 - M) + __expf(cntlog - M) + __expf(diag - M));
}

// ---------------- kernel 2: per-row contribution (wave per row) ----------------
__global__ void row_contrib(const float* __restrict__ F, const float* __restrict__ Imp,
                            const float* __restrict__ partials_row,
                            const float* __restrict__ colsum,
                            const int* __restrict__ counts,
                            const int* __restrict__ labels, float* __restrict__ blockSums) {
    const int lane = threadIdx.x & 63;
    const int wave = threadIdx.x >> 6;
    const int row = blockIdx.x * 4 + wave;

    // fp32 diagonal dot: 256 floats = 64 lanes * float4
    float4 a = reinterpret_cast<const float4*>(F + (size_t)row * D)[lane];
    float4 b = reinterpret_cast<const float4*>(Imp + (size_t)row * D)[lane];
    float dot = a.x * b.x + a.y * b.y + a.z * b.z + a.w * b.w;
#pragma unroll
    for (int off = 32; off > 0; off >>= 1) dot += __shfl_xor(dot, off, 64);

    __shared__ float sums[4];
    if (lane == 0) {
        const float diag = 2.0f * dot;                 // temperature 0.5
        const int cnt = counts[labels[row]] - 1;       // equal-label count excl. self
        const float cntlog = (cnt > 0) ? __logf((float)cnt) : -INFINITY;
        float S_row = 0.0f;
#pragma unroll
        for (int k = 0; k < NSLICE; ++k) S_row += partials_row[(size_t)row * NSLICE + k];
        const float S_col = colsum[row];
        const float lse_total = final_lse(S_row, cntlog, diag) + final_lse(S_col, cntlog, diag);
        sums[wave] = 2.0f * diag - lse_total;
    }
    __syncthreads();
    if (threadIdx.x == 0)
        blockSums[blockIdx.x] = sums[0] + sums[1] + sums[2] + sums[3];
}

// ---------------- kernel 3: final deterministic reduce ----------------
__global__ void final_reduce(const float* __restrict__ blockSums, float* __restrict__ out) {
    __shared__ float red[256];
    float v = 0.0f;
    for (int i = threadIdx.x; i < N / 4; i += 256) v += blockSums[i];
    red[threadIdx.x] = v;
    __syncthreads();
    for (int st = 128; st > 0; st >>= 1) {
        if (threadIdx.x < st) red[threadIdx.x] += red[threadIdx.x + st];
        __syncthreads();
    }
    if (threadIdx.x == 0) out[0] = -red[0] / (float)N;
}

extern "C" void kernel_launch(void* const* d_in, const int* in_sizes, int n_in,
                              void* d_out, int out_size, void* d_ws, size_t ws_size,
                              hipStream_t stream) {
    const float* F = (const float*)d_in[0];
    const float* Imp = (const float*)d_in[1];
    const int* labels = (const int*)d_in[2];
    float* out = (float*)d_out;

    char* ws = (char*)d_ws;
    size_t off = 0;
    ushort* Fb = (ushort*)(ws + off); off += (size_t)N * D * 2;               // 4 MB
    ushort* Ib = (ushort*)(ws + off); off += (size_t)N * D * 2;               // 4 MB
    float* partials_row = (float*)(ws + off); off += (size_t)N * NSLICE * 4;  // 1 MB
    float* partials_col = (float*)(ws + off); off += (size_t)NRB * N * 4;     // 1 MB
    float* colsum = (float*)(ws + off); off += (size_t)N * 4;                 // 32 KB
    float* blockSums = (float*)(ws + off); off += (size_t)(N / 4) * 4;        // 8 KB
    int* counts = (int*)(ws + off);

    dim3 cgrid((N * D / 4 + 255) / 256, 2);
    convert_bf16<<<cgrid, 256, 0, stream>>>(F, Imp, Fb, Ib);
    label_hist<<<1, 256, 0, stream>>>(labels, counts);

    dim3 g(NRB, NSLICE);
    tile_pass<<<g, 256, 0, stream>>>(Fb, Ib, labels, partials_row, partials_col);

    col_reduce<<<N / 256, 256, 0, stream>>>(partials_col, colsum);
    row_contrib<<<N / 4, 256, 0, stream>>>(F, Imp, partials_row, colsum, counts, labels, blockSums);
    final_reduce<<<1, 256, 0, stream>>>(blockSums, out);
}